// Round 1
// 1879.350 us; speedup vs baseline: 1.2337x; 1.2337x over previous
//
#include <hip/hip_runtime.h>

typedef __bf16 bf16x8 __attribute__((ext_vector_type(8)));
typedef float f32x4 __attribute__((ext_vector_type(4)));

#define MAXV 448.0f

__device__ __forceinline__ void gld_lds16(const void* g, void* l) {
  __builtin_amdgcn_global_load_lds(
      (const __attribute__((address_space(1))) void*)g,
      (__attribute__((address_space(3))) void*)l, 16, 0, 0);
}

__global__ void init_ws_kernel(unsigned int* p) {
  if (threadIdx.x < 2) p[threadIdx.x] = 0u;
}

__global__ void amax_kernel(const float* __restrict__ in, long n4, unsigned int* out) {
  long i0 = (long)blockIdx.x * blockDim.x + threadIdx.x;
  long stride = (long)gridDim.x * blockDim.x;
  const float4* in4 = (const float4*)in;
  float m = 0.0f;
  for (long i = i0; i < n4; i += stride) {
    float4 v = in4[i];
    m = fmaxf(m, fmaxf(fmaxf(fabsf(v.x), fabsf(v.y)), fmaxf(fabsf(v.z), fabsf(v.w))));
  }
  m = fminf(m, MAXV);  // amax of clipped == min(amax, 448)
#pragma unroll
  for (int off = 32; off >= 1; off >>= 1)
    m = fmaxf(m, __shfl_xor(m, off, 64));
  if ((threadIdx.x & 63) == 0) atomicMax(out, __float_as_uint(m));
}

// Fake-quantize one value into the SCALED domain, return bf16 bits (exact:
// result has a 4-bit significand).
__device__ __forceinline__ unsigned short fq1(float v, float scale) {
  float c = fminf(fmaxf(v, -MAXV), MAXV);
  float s = c * scale;
  float mag = fmaxf(fabsf(s), 1e-12f);          // always a normal fp32
  unsigned int u = __float_as_uint(mag);
  unsigned int E = u >> 23;                     // biased exponent
  float t = __uint_as_float((u & 0x007fffffu) | (130u << 23));
  float r = rintf(t);                           // round half-to-even (jnp.round)
  float q = r * __uint_as_float((E - 3u) << 23);  // r * 2^(e-3), exact
  float res = (s == 0.0f) ? 0.0f : copysignf(q, s);
  return (unsigned short)(__float_as_uint(res) >> 16);  // exact bf16 truncation
}

__global__ void quant_kernel(const float* __restrict__ in, unsigned short* __restrict__ out,
                             long n4, const unsigned int* __restrict__ amax_p) {
  float amax = fmaxf(__uint_as_float(*amax_p), 1e-12f);
  float scale = MAXV / amax;
  long i0 = (long)blockIdx.x * blockDim.x + threadIdx.x;
  long stride = (long)gridDim.x * blockDim.x;
  const float4* in4 = (const float4*)in;
  ushort4* out4 = (ushort4*)out;
  for (long i = i0; i < n4; i += stride) {
    float4 v = in4[i];
    ushort4 o;
    o.x = fq1(v.x, scale);
    o.y = fq1(v.y, scale);
    o.z = fq1(v.z, scale);
    o.w = fq1(v.w, scale);
    out4[i] = o;
  }
}

// ---------------------------------------------------------------------------
// 256x256 8-phase GEMM (learn_hip m201 template, plain HIP).
// C[m,n] = (sum_k A[m,k]*B[n,k]) * inv + bias[n];  A: MxK bf16, B: NxK bf16.
//
// Geometry: BM=BN=256, BK=64, 512 threads = 8 waves (2m x 4n), per-wave
// output 128x64 (8x4 frags of 16x16x32 MFMA).  LDS = 2 buf x (A 32KB + B
// 32KB) = 128 KiB.  Each half-tile (128 rows x 64 k) is stored k-block-major
// [kb:2][row:128][32 shorts] with st_16x32 swizzle byte^=((byte>>9)&1)<<5
// (engages all 32 banks on ds_read_b128).  global_load_lds writes LINEARLY;
// the swizzle is applied by pre-swizzling the global source address and
// swizzling the ds_read address (guide rule 21).
//
// Schedule: per tile T, 4 phases; phase r reads {r0: A i0-3 + B j0-1 (12),
// r1: B j2-3 (4), r2: A i4-7 (8), r3: none}; each phase stages ONE 16KB
// quantum (2 gld_lds/thread), staying 7 quanta (~2 tiles) ahead of
// consumption; vmcnt(6) once per tile (3 quanta in flight), vmcnt(0) only
// at the last boundary.  Every LDS region's overwrite is >=1 barrier after
// its last read (reads complete before the MFMA that precedes bar2).
// ---------------------------------------------------------------------------
__global__ __launch_bounds__(512, 2) void gemm256_kernel(
    const unsigned short* __restrict__ A, const unsigned short* __restrict__ B,
    const float* __restrict__ bias, const unsigned int* __restrict__ amax_ws,
    float* __restrict__ C, int M, int N, int K) {
  __shared__ __attribute__((aligned(16))) unsigned char lds[131072];

  const int tid = threadIdx.x;
  const int lane = tid & 63;
  const int wave = tid >> 6;
  const int wm = wave >> 2, wn = wave & 3;
  const int mfrag = lane & 15, kq = lane >> 4;
  const int kxor = (kq * 16) ^ (((mfrag >> 3) & 1) << 5);  // swizzled k-offset

  // XCD-aware block swizzle (gridDim.x % 8 == 0 here: 2048)
  const int nbn = N >> 8;
  const int wg = (blockIdx.x & 7) * (gridDim.x >> 3) + (blockIdx.x >> 3);
  const int bm = wg / nbn, bn = wg % nbn;

  const int nT = K >> 6;  // 64 k-tiles of BK=64

  // ---- staging constants (per-thread, computed once) ----
  // quantum chunk map: A q0 (rows 0-63 both kb blocks), A q1 (rows 64-127),
  // B q0 (rows 0-31 & 64-95), B q1 (rows 32-63 & 96-127); chunk = 16B.
  const int cA0 = ((tid >> 8) << 9) + (tid & 255);
  const int cB0 = ((tid >> 7) << 8) + (tid & 127);
  const int cAq[2] = {cA0, cA0 + 256};
  const int cBq[2] = {cB0, cB0 + 128};
  const unsigned short* sA[2][2];
  const unsigned short* sB[2][2];
  int dA[2][2], dB[2][2];
#pragma unroll
  for (int q = 0; q < 2; ++q) {
    {
      int c = cAq[q], row = (c >> 2) & 127, kb = c >> 9, ch = c & 3;
      int ko = kb * 32 + ((ch * 8) ^ (((row >> 3) & 1) << 4));  // pre-swizzled src
#pragma unroll
      for (int l = 0; l < 2; ++l) {
        sA[q][l] = A + (size_t)(bm * 256 + l * 128 + row) * K + ko;
        dA[q][l] = l * 16384 + c * 16;  // linear LDS dst (wave-base + lane*16)
      }
    }
    {
      int c = cBq[q], row = (c >> 2) & 127, kb = c >> 9, ch = c & 3;
      int ko = kb * 32 + ((ch * 8) ^ (((row >> 3) & 1) << 4));
#pragma unroll
      for (int l = 0; l < 2; ++l) {
        sB[q][l] = B + (size_t)(bn * 256 + l * 128 + row) * K + ko;
        dB[q][l] = 32768 + l * 16384 + c * 16;
      }
    }
  }

#define STAGE_A(qq, T2)                                              \
  do {                                                               \
    long ko_ = (long)(T2) * 64;                                      \
    int b2_ = ((T2) & 1) * 65536;                                    \
    gld_lds16(sA[qq][0] + ko_, lds + b2_ + dA[qq][0]);               \
    gld_lds16(sA[qq][1] + ko_, lds + b2_ + dA[qq][1]);               \
  } while (0)
#define STAGE_B(qq, T2)                                              \
  do {                                                               \
    long ko_ = (long)(T2) * 64;                                      \
    int b2_ = ((T2) & 1) * 65536;                                    \
    gld_lds16(sB[qq][0] + ko_, lds + b2_ + dB[qq][0]);               \
    gld_lds16(sB[qq][1] + ko_, lds + b2_ + dB[qq][1]);               \
  } while (0)

  // prologue: quanta 0..6 = tile0 {Aq0,Bq0,Bq1,Aq1}, tile1 {Aq0,Bq0,Bq1}
  STAGE_A(0, 0);
  STAGE_B(0, 0);
  STAGE_B(1, 0);
  STAGE_A(1, 0);
  if (nT > 1) {
    STAGE_A(0, 1);
    STAGE_B(0, 1);
    STAGE_B(1, 1);
    asm volatile("s_waitcnt vmcnt(6)" ::: "memory");  // tile0 resident
  } else {
    asm volatile("s_waitcnt vmcnt(0)" ::: "memory");
  }
  __builtin_amdgcn_s_barrier();

  const unsigned char* ldsA0 = lds + wm * 16384 + mfrag * 64 + kxor;
  const unsigned char* ldsB0 = lds + 32768 + (wn >> 1) * 16384 + (wn & 1) * 4096 + mfrag * 64 + kxor;

  f32x4 acc[8][4] = {};
  bf16x8 af[4][2], bf[4][2];

  for (int T = 0; T < nT; ++T) {
    const unsigned char* pA = ldsA0 + (T & 1) * 65536;
    const unsigned char* pB = ldsB0 + (T & 1) * 65536;

    // ---- phase r0: read A i0-3 + B j0-1; stage (T+1).Aq1; mfma quad(0,0)
#pragma unroll
    for (int i = 0; i < 4; ++i)
#pragma unroll
      for (int ks = 0; ks < 2; ++ks)
        af[i][ks] = *(const bf16x8*)(pA + ks * 8192 + i * 1024);
#pragma unroll
    for (int j = 0; j < 2; ++j)
#pragma unroll
      for (int ks = 0; ks < 2; ++ks)
        bf[j][ks] = *(const bf16x8*)(pB + ks * 8192 + j * 1024);
    if (T + 1 < nT) STAGE_A(1, T + 1);
    __builtin_amdgcn_s_barrier();
    __builtin_amdgcn_s_setprio(1);
#pragma unroll
    for (int i = 0; i < 4; ++i)
#pragma unroll
      for (int j = 0; j < 2; ++j) {
        acc[i][j] = __builtin_amdgcn_mfma_f32_16x16x32_bf16(af[i][0], bf[j][0], acc[i][j], 0, 0, 0);
        acc[i][j] = __builtin_amdgcn_mfma_f32_16x16x32_bf16(af[i][1], bf[j][1], acc[i][j], 0, 0, 0);
      }
    __builtin_amdgcn_s_setprio(0);
    __builtin_amdgcn_s_barrier();

    // ---- phase r1: read B j2-3; stage (T+2).Aq0; mfma quad(0,1)
#pragma unroll
    for (int j = 2; j < 4; ++j)
#pragma unroll
      for (int ks = 0; ks < 2; ++ks)
        bf[j][ks] = *(const bf16x8*)(pB + ks * 8192 + j * 1024);
    if (T + 2 < nT) STAGE_A(0, T + 2);
    __builtin_amdgcn_s_barrier();
    __builtin_amdgcn_s_setprio(1);
#pragma unroll
    for (int i = 0; i < 4; ++i)
#pragma unroll
      for (int j = 2; j < 4; ++j) {
        acc[i][j] = __builtin_amdgcn_mfma_f32_16x16x32_bf16(af[i][0], bf[j][0], acc[i][j], 0, 0, 0);
        acc[i][j] = __builtin_amdgcn_mfma_f32_16x16x32_bf16(af[i][1], bf[j][1], acc[i][j], 0, 0, 0);
      }
    __builtin_amdgcn_s_setprio(0);
    __builtin_amdgcn_s_barrier();

    // ---- phase r2: read A i4-7; stage (T+2).Bq0; mfma quad(1,0)
#pragma unroll
    for (int i = 0; i < 4; ++i)
#pragma unroll
      for (int ks = 0; ks < 2; ++ks)
        af[i][ks] = *(const bf16x8*)(pA + ks * 8192 + (i + 4) * 1024);
    if (T + 2 < nT) STAGE_B(0, T + 2);
    __builtin_amdgcn_s_barrier();
    __builtin_amdgcn_s_setprio(1);
#pragma unroll
    for (int i = 0; i < 4; ++i)
#pragma unroll
      for (int j = 0; j < 2; ++j) {
        acc[i + 4][j] = __builtin_amdgcn_mfma_f32_16x16x32_bf16(af[i][0], bf[j][0], acc[i + 4][j], 0, 0, 0);
        acc[i + 4][j] = __builtin_amdgcn_mfma_f32_16x16x32_bf16(af[i][1], bf[j][1], acc[i + 4][j], 0, 0, 0);
      }
    __builtin_amdgcn_s_setprio(0);
    __builtin_amdgcn_s_barrier();

    // ---- phase r3: stage (T+2).Bq1; counted vmcnt; mfma quad(1,1)
    if (T + 2 < nT) STAGE_B(1, T + 2);
    if (T < nT - 2) {
      asm volatile("s_waitcnt vmcnt(6)" ::: "memory");  // next tile resident, 3 quanta in flight
    } else {
      asm volatile("s_waitcnt vmcnt(0)" ::: "memory");  // epilogue drain
    }
    __builtin_amdgcn_s_barrier();
    __builtin_amdgcn_s_setprio(1);
#pragma unroll
    for (int i = 0; i < 4; ++i)
#pragma unroll
      for (int j = 2; j < 4; ++j) {
        acc[i + 4][j] = __builtin_amdgcn_mfma_f32_16x16x32_bf16(af[i][0], bf[j][0], acc[i + 4][j], 0, 0, 0);
        acc[i + 4][j] = __builtin_amdgcn_mfma_f32_16x16x32_bf16(af[i][1], bf[j][1], acc[i + 4][j], 0, 0, 0);
      }
    __builtin_amdgcn_s_setprio(0);
    __builtin_amdgcn_s_barrier();
  }
#undef STAGE_A
#undef STAGE_B

  // epilogue: rescale + bias. C/D layout: col=lane&15, row=(lane>>4)*4+reg
  float amx = fmaxf(__uint_as_float(amax_ws[0]), 1e-12f);
  float amw = fmaxf(__uint_as_float(amax_ws[1]), 1e-12f);
  float sx = MAXV / amx, sw = MAXV / amw;
  float inv = 1.0f / (sx * sw);

  const int rb = bm * 256 + wm * 128 + (lane >> 4) * 4;
  const int cb = bn * 256 + wn * 64 + (lane & 15);
  float bv[4];
#pragma unroll
  for (int j = 0; j < 4; ++j) bv[j] = bias[cb + j * 16];
#pragma unroll
  for (int i = 0; i < 8; ++i)
#pragma unroll
    for (int j = 0; j < 4; ++j) {
      const int col = cb + j * 16;
#pragma unroll
      for (int r = 0; r < 4; ++r)
        C[(long)(rb + i * 16 + r) * N + col] = acc[i][j][r] * inv + bv[j];
    }
}

extern "C" void kernel_launch(void* const* d_in, const int* in_sizes, int n_in,
                              void* d_out, int out_size, void* d_ws, size_t ws_size,
                              hipStream_t stream) {
  const float* x = (const float*)d_in[0];
  const float* w = (const float*)d_in[1];
  const float* bias = (const float*)d_in[2];
  float* out = (float*)d_out;

  const long NX = in_sizes[0];       // B*S*IN_F = 33554432
  const long NW = in_sizes[1];       // OUT_F*IN_F = 67108864
  const int N = in_sizes[2];         // OUT_F = 16384
  const int K = (int)(NW / N);       // 4096
  const int M = (int)(NX / K);       // 8192

  unsigned int* amax = (unsigned int*)d_ws;
  unsigned short* xq = (unsigned short*)((char*)d_ws + 256);
  unsigned short* wq = (unsigned short*)((char*)d_ws + 256 + NX * 2);

  init_ws_kernel<<<1, 64, 0, stream>>>(amax);
  amax_kernel<<<1024, 256, 0, stream>>>(x, NX >> 2, amax + 0);
  amax_kernel<<<2048, 256, 0, stream>>>(w, NW >> 2, amax + 1);
  quant_kernel<<<2048, 256, 0, stream>>>(x, xq, NX >> 2, amax + 0);
  quant_kernel<<<2048, 256, 0, stream>>>(w, wq, NW >> 2, amax + 1);

  dim3 grid((unsigned)((M / 256) * (N / 256)));  // 2048, %8 == 0
  gemm256_kernel<<<grid, 512, 0, stream>>>(xq, wq, bias, amax, out, M, N, K);
}